// Round 7
// baseline (262.138 us; speedup 1.0000x reference)
//
#include <hip/hip_runtime.h>

typedef __attribute__((ext_vector_type(8))) short bf16x8;
typedef __attribute__((ext_vector_type(4))) float f32x4;

#define LOG2E 1.44269504088896340736f

// Average-trace constant from the Python module (length 120).
__device__ __constant__ float AVG_D[120] = {
    0.0256f,0.0823f,0.1157f,0.1315f,0.1366f,0.1369f,0.1347f,0.1308f,0.1259f,0.1205f,
    0.1146f,0.1086f,0.1028f,0.0970f,0.0913f,0.0858f,0.0805f,0.0756f,0.0708f,0.0664f,
    0.0623f,0.0584f,0.0549f,0.0515f,0.0485f,0.0456f,0.0429f,0.0404f,0.0381f,0.0360f,
    0.0340f,0.0321f,0.0304f,0.0287f,0.0272f,0.0258f,0.0245f,0.0233f,0.0222f,0.0211f,
    0.0201f,0.0191f,0.0182f,0.0173f,0.0165f,0.0158f,0.0150f,0.0143f,0.0137f,0.0130f,
    0.0125f,0.0119f,0.0114f,0.0108f,0.0104f,0.0099f,0.0095f,0.0091f,0.0087f,0.0083f,
    0.0080f,0.0077f,0.0074f,0.0071f,0.0068f,0.0065f,0.0062f,0.0060f,0.0058f,0.0055f,
    0.0053f,0.0050f,0.0049f,0.0047f,0.0045f,0.0044f,0.0042f,0.0040f,0.0039f,0.0038f,
    0.0036f,0.0034f,0.0033f,0.0032f,0.0031f,0.0030f,0.0029f,0.0028f,0.0027f,0.0026f,
    0.0025f,0.0024f,0.0023f,0.0022f,0.0021f,0.0021f,0.0020f,0.0019f,0.0018f,0.0018f,
    0.0017f,0.0017f,0.0016f,0.0016f,0.0015f,0.0015f,0.0014f,0.0014f,0.0013f,0.0013f,
    0.0013f,0.0012f,0.0012f,0.0011f,0.0011f,0.0011f,0.0010f,0.0010f,0.0010f,0.0009f
};

__device__ __forceinline__ float sig2(float x) {
    return __builtin_amdgcn_rcpf(1.0f + __builtin_amdgcn_exp2f(x));
}
__device__ __forceinline__ float tanh2(float x) {
    return fmaf(2.0f, __builtin_amdgcn_rcpf(1.0f + __builtin_amdgcn_exp2f(x)), -1.0f);
}
__device__ __forceinline__ unsigned short tb(float x) {          // truncate fp32 -> bf16
    return (unsigned short)(__float_as_uint(x) >> 16);
}
__device__ __forceinline__ float fb(unsigned short h) {
    return __uint_as_float(((unsigned)h) << 16);
}

// A[128 rows][32 k], row r = u*4+q, PRE-SCALED by sc(q) = -log2e (i,f,o) / -2log2e (g):
//   u<30,  k<30 : sc*W_hh1[(q*30+u)*30+k]
//   u<30,  k==30: sc*W_ih1[(q*30+u)*13+12]   (avg column; B k=30 slot = AVG[t])
//   u==30, k<30 : sc*W_ih2[q*30+k]           (LSTM2 input dot rides the same MFMA)
// ws layout (float*): ushort whi[4096] @0; ushort wlo @2048; float bconst[128] @4096
//                     float wih1f[128*12] @4224; u32 avgpk[121] @5760 (hi|lo<<16)
__global__ void pack_weights(const float* __restrict__ w_ih1,
                             const float* __restrict__ w_hh1,
                             const float* __restrict__ b1,
                             const float* __restrict__ w_ih2,
                             const float* __restrict__ b2,
                             float* __restrict__ ws) {
    unsigned short* whi = (unsigned short*)ws;
    unsigned short* wlo = (unsigned short*)(ws + 2048);
    float* bconst = ws + 4096;
    float* wih1f  = ws + 4224;
    unsigned* avgpk = (unsigned*)(ws + 5760);
    const int tid = threadIdx.x;
    for (int idx = tid; idx < 4096; idx += 256) {
        const int T = idx >> 9, lane = (idx >> 3) & 63, j = idx & 7;
        const int r = 16 * T + (lane & 15);
        const int k = ((lane >> 4) & 3) * 8 + j;
        const int u = r >> 2, q = r & 3;
        const float sc = (q == 2) ? (-2.0f * LOG2E) : (-LOG2E);
        float v = 0.0f;
        if (u < 30) {
            if (k < 30)       v = w_hh1[(q * 30 + u) * 30 + k];
            else if (k == 30) v = w_ih1[(q * 30 + u) * 13 + 12];
        } else if (u == 30 && k < 30) {
            v = w_ih2[q * 30 + k];
        }
        v *= sc;
        const unsigned short hi = tb(v);
        whi[idx] = hi;
        wlo[idx] = tb(v - fb(hi));
    }
    for (int r = tid; r < 128; r += 256) {
        const int u = r >> 2, q = r & 3;
        const float sc = (q == 2) ? (-2.0f * LOG2E) : (-LOG2E);
        bconst[r] = sc * ((u < 30) ? b1[q * 30 + u] : ((u == 30) ? b2[q] : 0.0f));
    }
    for (int idx = tid; idx < 1536; idx += 256) {
        const int r = idx / 12, d = idx % 12;
        const int u = r >> 2, q = r & 3;
        const float sc = (q == 2) ? (-2.0f * LOG2E) : (-LOG2E);
        wih1f[idx] = (u < 30) ? sc * w_ih1[(q * 30 + u) * 13 + d] : 0.0f;
    }
    for (int t = tid; t < 121; t += 256) {
        const float a = (t < 120) ? AVG_D[t] : 0.0f;
        const unsigned short hi = tb(a);
        const unsigned short lo = tb(a - fb(hi));
        avgpk[t] = (unsigned)hi | ((unsigned)lo << 16);
    }
}

// R12/R13: trans-pipe TLP. R10 measured: 211us, Occ 34.7%, VALUBusy 73.7%,
// MfmaUtil 20.1%, VGPR 64. Cycle-model fit (R8+R10) says v_exp/v_rcp occupy
// ~16 cyc/wave64 of issue — the 28 trans/wave-step dominate VALUBusy; 26%
// idle = trans-latency gaps 4 waves/SIMD can't fill. Fix: split the 128
// A-rows across 4 COOPERATING waves (wave w owns tiles 2w,2w+1 = units
// 8w..8w+7; wave3 owns the LSTM2 row u=30). Aggregate per-SIMD issue is
// ~unchanged (trans splits cleanly; only B-build duplicates) but waves/SIMD
// goes 4 -> 8 (2048 blocks x 4 waves; 8 blocks/CU x 4 = 32 waves/CU = max).
// Same math / LDS layout / one __syncthreads per step as verified R10.
__global__ __launch_bounds__(256, 8)
void lstm_mfma_kernel(const float* __restrict__ feat,
                      const float* __restrict__ w_hh2,
                      const float* __restrict__ ws,
                      float* __restrict__ out) {
    __shared__ __align__(16) unsigned hx[2][16 * 36];  // 4.6 KB, double-buffered h
    __shared__ __align__(16) float out_s[16 * 124];    // h2 staging, 7.9 KB

    const int tid  = threadIdx.x;
    const int lane = tid & 63;
    const int wv   = __builtin_amdgcn_readfirstlane(tid >> 6);  // 0..3
    const int s    = lane & 15;
    const int quad = lane >> 4;
    const int seq  = blockIdx.x * 16 + s;
    const unsigned* avgpk = (const unsigned*)(ws + 5760);

    // zero both h buffers (pads stay 0), then seed AVG[0] in buf0
    for (int i = tid; i < 2 * 16 * 36; i += 256) (&hx[0][0])[i] = 0u;
    __syncthreads();
    if (tid < 16) hx[0][tid * 36 + 30] = avgpk[0];

    // ---- A fragments: this wave's 2 tiles (Tg = 2*wv + T) ----
    bf16x8 Ahi[2], Alo[2];
    {
        const unsigned short* whi = (const unsigned short*)ws;
        const unsigned short* wlo = (const unsigned short*)(ws + 2048);
#pragma unroll
        for (int T = 0; T < 2; T++) {
            const int Tg = 2 * wv + T;
            Ahi[T] = *(const bf16x8*)(whi + Tg * 512 + lane * 8);
            Alo[T] = *(const bf16x8*)(wlo + Tg * 512 + lane * 8);
        }
    }

    // ---- per-sequence constant projection (scaled domain), 2 tiles ----
    float f0[12];
    {
        const float4* fp = reinterpret_cast<const float4*>(feat + seq * 12);
        float4 A = fp[0], B = fp[1], C = fp[2];
        f0[0]=A.x; f0[1]=A.y; f0[2]=A.z; f0[3]=A.w;
        f0[4]=B.x; f0[5]=B.y; f0[6]=B.z; f0[7]=B.w;
        f0[8]=C.x; f0[9]=C.y; f0[10]=C.z; f0[11]=C.w;
    }
    f32x4 projb[2];
    {
        const float* bconst = ws + 4096;
        const float* wih1f  = ws + 4224;
#pragma unroll
        for (int T = 0; T < 2; T++) {
#pragma unroll
            for (int g = 0; g < 4; g++) {
                const int r = 16 * (2 * wv + T) + 4 * quad + g;
                float acc = bconst[r];
#pragma unroll
                for (int d = 0; d < 12; d++) acc = fmaf(f0[d], wih1f[r * 12 + d], acc);
                projb[T][g] = acc;
            }
        }
    }

    float c1[2];
#pragma unroll
    for (int T = 0; T < 2; T++) c1[T] = 0.0f;
    float h2 = 0.0f, c2 = 0.0f;
    const float whs0 = -LOG2E * w_hh2[0];
    const float whs1 = -LOG2E * w_hh2[1];
    const float whs2 = -2.0f * LOG2E * w_hh2[2];
    const float whs3 = -LOG2E * w_hh2[3];

    __syncthreads();   // AVG seed visible to all waves

    unsigned apk_cur = avgpk[1];   // AVG slot value for the t=0 update

#pragma unroll 1
    for (int t = 0; t <= 120; t++) {
        const unsigned* hb = hx[t & 1];
        unsigned*       hn = hx[(t & 1) ^ 1];

        // prefetch next AVG word a full iteration early (off the serial chain)
        const unsigned apk = apk_cur;
        apk_cur = avgpk[(t + 2 <= 120) ? (t + 2) : 120];

        // ---- B fragment: 2 ds_read_b128 + 8 perms (units 8q..8q+7, seq s) ----
        const uint4 Ra = *reinterpret_cast<const uint4*>(hb + s * 36 + 8 * quad);
        const uint4 Rb = *reinterpret_cast<const uint4*>(hb + s * 36 + 8 * quad + 4);
        union { int4 i; bf16x8 v; } ubh, ubl;
        ubh.i.x = (int)__builtin_amdgcn_perm(Ra.y, Ra.x, 0x05040100u);
        ubh.i.y = (int)__builtin_amdgcn_perm(Ra.w, Ra.z, 0x05040100u);
        ubh.i.z = (int)__builtin_amdgcn_perm(Rb.y, Rb.x, 0x05040100u);
        ubh.i.w = (int)__builtin_amdgcn_perm(Rb.w, Rb.z, 0x05040100u);
        ubl.i.x = (int)__builtin_amdgcn_perm(Ra.y, Ra.x, 0x07060302u);
        ubl.i.y = (int)__builtin_amdgcn_perm(Ra.w, Ra.z, 0x07060302u);
        ubl.i.z = (int)__builtin_amdgcn_perm(Rb.y, Rb.x, 0x07060302u);
        ubl.i.w = (int)__builtin_amdgcn_perm(Rb.w, Rb.z, 0x07060302u);
        const bf16x8 Bhi = ubh.v, Blo = ubl.v;

        // ---- 6 MFMAs: D = Ahi*Bhi + Ahi*Blo + Alo*Bhi + projb ----
        f32x4 D[2];
#pragma unroll
        for (int T = 0; T < 2; T++)
            D[T] = __builtin_amdgcn_mfma_f32_16x16x32_bf16(Alo[T], Bhi, projb[T], 0, 0, 0);
#pragma unroll
        for (int T = 0; T < 2; T++)
            D[T] = __builtin_amdgcn_mfma_f32_16x16x32_bf16(Ahi[T], Blo, D[T], 0, 0, 0);
#pragma unroll
        for (int T = 0; T < 2; T++)
            D[T] = __builtin_amdgcn_mfma_f32_16x16x32_bf16(Ahi[T], Bhi, D[T], 0, 0, 0);

        // ---- LSTM2 cell for step t-1 (wave3 local tile1 = rows 120..123) ----
        if (wv == 3 && t >= 1 && quad == 2) {
            const float g0 = fmaf(h2, whs0, D[1][0]);
            const float g1 = fmaf(h2, whs1, D[1][1]);
            const float g2 = fmaf(h2, whs2, D[1][2]);
            const float g3 = fmaf(h2, whs3, D[1][3]);
            c2 = sig2(g1) * c2 + sig2(g0) * tanh2(g2);
            h2 = sig2(g3) * tanh2(c2 * (-2.0f * LOG2E));
            out_s[s * 124 + (t - 1)] = h2;
        }

        // ---- LSTM1 activations (u=8wv+4T+quad); write packed bf16 h_t ----
        if (t < 120) {
#pragma unroll
            for (int T = 0; T < 2; T++) {
                const int u = 8 * wv + 4 * T + quad;
                unsigned v = 0u;
                if (u < 30) {
                    const float ei = __builtin_amdgcn_exp2f(D[T][0]);
                    const float ef = __builtin_amdgcn_exp2f(D[T][1]);
                    const float eg = __builtin_amdgcn_exp2f(D[T][2]);
                    const float eo = __builtin_amdgcn_exp2f(D[T][3]);
                    const float pi_ = 1.0f + ei, pf = 1.0f + ef;
                    const float pg  = 1.0f + eg, po = 1.0f + eo;
                    const float pig = pi_ * pg;
                    const float num = fmaf(c1[T], pig, (1.0f - eg) * pf);
                    const float ck  = num * __builtin_amdgcn_rcpf(pf * pig);
                    c1[T] = ck;
                    float carg = -2.0f * LOG2E * ck;
                    carg = fminf(fmaxf(carg, -80.0f), 80.0f);
                    const float ec = __builtin_amdgcn_exp2f(carg);
                    const float hk = (1.0f - ec) *
                                     __builtin_amdgcn_rcpf(po * (1.0f + ec));
                    const unsigned hbits = __float_as_uint(hk);
                    const float rem = hk - __uint_as_float(hbits & 0xffff0000u);
                    v = __builtin_amdgcn_perm(__float_as_uint(rem), hbits, 0x07060302u);
                } else if (u == 30) {
                    v = apk;                      // AVG[t+1] slot (wave3, T=1, quad=2)
                }
                hn[s * 36 + u] = v;               // u=31 lane writes 0 (pad)
            }
            __syncthreads();                      // h_t quarters visible to all waves
        }
    }

    __syncthreads();
    // ---- coalesced flush: 16 seq x 120 t = 480 float4 by 256 threads ----
    float* outb = out + (size_t)blockIdx.x * 16 * 120;
#pragma unroll
    for (int it = 0; it < 2; it++) {
        const int fi = it * 256 + tid;
        if (fi < 480) {
            const int sq = fi / 30, j = fi % 30;
            const float4 v = *reinterpret_cast<const float4*>(&out_s[sq * 124 + j * 4]);
            *reinterpret_cast<float4*>(&outb[sq * 120 + j * 4]) = v;
        }
    }
}

extern "C" void kernel_launch(void* const* d_in, const int* in_sizes, int n_in,
                              void* d_out, int out_size, void* d_ws, size_t ws_size,
                              hipStream_t stream) {
    (void)in_sizes; (void)n_in; (void)out_size; (void)ws_size;
    const float* feat  = (const float*)d_in[0];
    const float* w_ih1 = (const float*)d_in[1];
    const float* w_hh1 = (const float*)d_in[2];
    const float* b1    = (const float*)d_in[3];
    const float* w_ih2 = (const float*)d_in[4];
    const float* w_hh2 = (const float*)d_in[5];
    const float* b2    = (const float*)d_in[6];
    float* ws  = (float*)d_ws;
    float* out = (float*)d_out;

    hipLaunchKernelGGL(pack_weights, dim3(1), dim3(256), 0, stream,
                       w_ih1, w_hh1, b1, w_ih2, b2, ws);
    hipLaunchKernelGGL(lstm_mfma_kernel, dim3(2048), dim3(256), 0, stream,
                       feat, w_hh2, ws, out);
}

// Round 9
// 246.727 us; speedup vs baseline: 1.0625x; 1.0625x over previous
//
#include <hip/hip_runtime.h>

typedef __attribute__((ext_vector_type(8))) short bf16x8;
typedef __attribute__((ext_vector_type(4))) float f32x4;

#define LOG2E 1.44269504088896340736f

// Average-trace constant from the Python module (length 120).
__device__ __constant__ float AVG_D[120] = {
    0.0256f,0.0823f,0.1157f,0.1315f,0.1366f,0.1369f,0.1347f,0.1308f,0.1259f,0.1205f,
    0.1146f,0.1086f,0.1028f,0.0970f,0.0913f,0.0858f,0.0805f,0.0756f,0.0708f,0.0664f,
    0.0623f,0.0584f,0.0549f,0.0515f,0.0485f,0.0456f,0.0429f,0.0404f,0.0381f,0.0360f,
    0.0340f,0.0321f,0.0304f,0.0287f,0.0272f,0.0258f,0.0245f,0.0233f,0.0222f,0.0211f,
    0.0201f,0.0191f,0.0182f,0.0173f,0.0165f,0.0158f,0.0150f,0.0143f,0.0137f,0.0130f,
    0.0125f,0.0119f,0.0114f,0.0108f,0.0104f,0.0099f,0.0095f,0.0091f,0.0087f,0.0083f,
    0.0080f,0.0077f,0.0074f,0.0071f,0.0068f,0.0065f,0.0062f,0.0060f,0.0058f,0.0055f,
    0.0053f,0.0050f,0.0049f,0.0047f,0.0045f,0.0044f,0.0042f,0.0040f,0.0039f,0.0038f,
    0.0036f,0.0034f,0.0033f,0.0032f,0.0031f,0.0030f,0.0029f,0.0028f,0.0027f,0.0026f,
    0.0025f,0.0024f,0.0023f,0.0022f,0.0021f,0.0021f,0.0020f,0.0019f,0.0018f,0.0018f,
    0.0017f,0.0017f,0.0016f,0.0016f,0.0015f,0.0015f,0.0014f,0.0014f,0.0013f,0.0013f,
    0.0013f,0.0012f,0.0012f,0.0011f,0.0011f,0.0011f,0.0010f,0.0010f,0.0010f,0.0009f
};

__device__ __forceinline__ float sig2(float x) {
    return __builtin_amdgcn_rcpf(1.0f + __builtin_amdgcn_exp2f(x));
}
__device__ __forceinline__ float tanh2(float x) {
    return fmaf(2.0f, __builtin_amdgcn_rcpf(1.0f + __builtin_amdgcn_exp2f(x)), -1.0f);
}
__device__ __forceinline__ unsigned short tb(float x) {          // truncate fp32 -> bf16
    return (unsigned short)(__float_as_uint(x) >> 16);
}
__device__ __forceinline__ float fb(unsigned short h) {
    return __uint_as_float(((unsigned)h) << 16);
}

// A[128 rows][32 k], row r = u*4+q, PRE-SCALED by sc(q) = -log2e (i,f,o) / -2log2e (g):
//   u<30,  k<30 : sc*W_hh1[(q*30+u)*30+k]
//   u<30,  k==30: sc*W_ih1[(q*30+u)*13+12]   (avg column; B k=30 slot = AVG[t])
//   u==30, k<30 : sc*W_ih2[q*30+k]           (LSTM2 input dot rides the same MFMA)
// ws layout (float*): ushort whi[4096] @0; ushort wlo @2048; float bconst[128] @4096
//                     float wih1f[128*12] @4224; u32 avgpk[121] @5760 (hi|lo<<16)
__global__ void pack_weights(const float* __restrict__ w_ih1,
                             const float* __restrict__ w_hh1,
                             const float* __restrict__ b1,
                             const float* __restrict__ w_ih2,
                             const float* __restrict__ b2,
                             float* __restrict__ ws) {
    unsigned short* whi = (unsigned short*)ws;
    unsigned short* wlo = (unsigned short*)(ws + 2048);
    float* bconst = ws + 4096;
    float* wih1f  = ws + 4224;
    unsigned* avgpk = (unsigned*)(ws + 5760);
    const int tid = threadIdx.x;
    for (int idx = tid; idx < 4096; idx += 256) {
        const int T = idx >> 9, lane = (idx >> 3) & 63, j = idx & 7;
        const int r = 16 * T + (lane & 15);
        const int k = ((lane >> 4) & 3) * 8 + j;
        const int u = r >> 2, q = r & 3;
        const float sc = (q == 2) ? (-2.0f * LOG2E) : (-LOG2E);
        float v = 0.0f;
        if (u < 30) {
            if (k < 30)       v = w_hh1[(q * 30 + u) * 30 + k];
            else if (k == 30) v = w_ih1[(q * 30 + u) * 13 + 12];
        } else if (u == 30 && k < 30) {
            v = w_ih2[q * 30 + k];
        }
        v *= sc;
        const unsigned short hi = tb(v);
        whi[idx] = hi;
        wlo[idx] = tb(v - fb(hi));
    }
    for (int r = tid; r < 128; r += 256) {
        const int u = r >> 2, q = r & 3;
        const float sc = (q == 2) ? (-2.0f * LOG2E) : (-LOG2E);
        bconst[r] = sc * ((u < 30) ? b1[q * 30 + u] : ((u == 30) ? b2[q] : 0.0f));
    }
    for (int idx = tid; idx < 1536; idx += 256) {
        const int r = idx / 12, d = idx % 12;
        const int u = r >> 2, q = r & 3;
        const float sc = (q == 2) ? (-2.0f * LOG2E) : (-LOG2E);
        wih1f[idx] = (u < 30) ? sc * w_ih1[(q * 30 + u) * 13 + d] : 0.0f;
    }
    for (int t = tid; t < 121; t += 256) {
        const float a = (t < 120) ? AVG_D[t] : 0.0f;
        const unsigned short hi = tb(a);
        const unsigned short lo = tb(a - fb(hi));
        avgpk[t] = (unsigned)hi | ((unsigned)lo << 16);
    }
}

// R14/R15: issue-count trim on the R10 2-wave structure (measured fastest:
// 211us vs R12 4-wave 216us — issue-port bound; VALUBusy*dur ~ 3100-3300
// cyc/step across R8/R10/R12; trans ops ~16cyc/wave64 dominate). Changes:
// (1) hi/lo SPLIT LDS (ushort arrays, stride 40 = 16B-aligned, <=2-way banks):
//     B fragment = 2 direct ds_read_b128, the 8 v_perm/wave-step are GONE and
//     ds_read feeds MFMA directly (shorter post-barrier chain).
// (2) h-path rcp PAIRING across cell pairs (0,1),(2,3): 4 rcp -> 2 rcp + 8
//     mul. carg clamp tightened +-80 -> +-20 (tanh saturated to 1e-12) so
//     paired products can't overflow (|preact|<=16 => Ba<=2^43, pair<=2^86);
//     dead cell (u>=30) masked to B=1.0 so live hka[2] stays exact.
// (3) per-cell math unguarded (EXEC-masked lanes cost identical issue);
//     only the h stores are overridden for u==30 (AVG) / u==31 (pad).
__global__ __launch_bounds__(128, 4)
void lstm_mfma_kernel(const float* __restrict__ feat,
                      const float* __restrict__ w_hh2,
                      const float* __restrict__ ws,
                      float* __restrict__ out) {
    __shared__ __align__(16) unsigned short hhi[2][16 * 40];  // 2.5 KB x2 bufs
    __shared__ __align__(16) unsigned short hlo[2][16 * 40];  // 2.5 KB x2 bufs
    __shared__ __align__(16) float out_s[16 * 124];           // h2 staging 7.9 KB

    const int tid  = threadIdx.x;
    const int lane = tid & 63;
    const int wv   = __builtin_amdgcn_readfirstlane(tid >> 6) & 1;
    const int s    = lane & 15;
    const int quad = lane >> 4;
    const int seq  = blockIdx.x * 16 + s;
    const unsigned* avgpk = (const unsigned*)(ws + 5760);

    // zero both hi/lo buffers (pads stay 0)
    {
        unsigned* zh = (unsigned*)(&hhi[0][0]);
        unsigned* zl = (unsigned*)(&hlo[0][0]);
        for (int i = tid; i < 640; i += 128) { zh[i] = 0u; zl[i] = 0u; }
    }
    __syncthreads();
    if (tid < 16) {
        const unsigned a0 = avgpk[0];
        hhi[0][tid * 40 + 30] = (unsigned short)a0;          // hi half
        hlo[0][tid * 40 + 30] = (unsigned short)(a0 >> 16);  // lo half
    }

    // ---- A fragments: this wave's 4 tiles (Tg = 4*wv + T) ----
    bf16x8 Ahi[4], Alo[4];
    {
        const unsigned short* wahi = (const unsigned short*)ws;
        const unsigned short* walo = (const unsigned short*)(ws + 2048);
#pragma unroll
        for (int T = 0; T < 4; T++) {
            const int Tg = 4 * wv + T;
            Ahi[T] = *(const bf16x8*)(wahi + Tg * 512 + lane * 8);
            Alo[T] = *(const bf16x8*)(walo + Tg * 512 + lane * 8);
        }
    }

    // ---- per-sequence constant projection (scaled domain), 4 tiles ----
    float f0[12];
    {
        const float4* fp = reinterpret_cast<const float4*>(feat + seq * 12);
        float4 A = fp[0], B = fp[1], C = fp[2];
        f0[0]=A.x; f0[1]=A.y; f0[2]=A.z; f0[3]=A.w;
        f0[4]=B.x; f0[5]=B.y; f0[6]=B.z; f0[7]=B.w;
        f0[8]=C.x; f0[9]=C.y; f0[10]=C.z; f0[11]=C.w;
    }
    f32x4 projb[4];
    {
        const float* bconst = ws + 4096;
        const float* wih1f  = ws + 4224;
#pragma unroll
        for (int T = 0; T < 4; T++) {
#pragma unroll
            for (int g = 0; g < 4; g++) {
                const int r = 16 * (4 * wv + T) + 4 * quad + g;
                float acc = bconst[r];
#pragma unroll
                for (int d = 0; d < 12; d++) acc = fmaf(f0[d], wih1f[r * 12 + d], acc);
                projb[T][g] = acc;
            }
        }
    }

    float c1[4];
#pragma unroll
    for (int T = 0; T < 4; T++) c1[T] = 0.0f;
    float h2 = 0.0f, c2 = 0.0f;
    const float whs0 = -LOG2E * w_hh2[0];
    const float whs1 = -LOG2E * w_hh2[1];
    const float whs2 = -2.0f * LOG2E * w_hh2[2];
    const float whs3 = -LOG2E * w_hh2[3];

    __syncthreads();   // AVG seed visible to both waves

    unsigned apk_cur = avgpk[1];   // AVG slot value for the t=0 update

#pragma unroll 1
    for (int t = 0; t <= 120; t++) {
        const int buf = t & 1;
        const unsigned short* bh = hhi[buf];
        const unsigned short* bl = hlo[buf];
        unsigned short* nh = hhi[buf ^ 1];
        unsigned short* nl = hlo[buf ^ 1];

        // prefetch next AVG word a full iteration early (off the serial chain)
        const unsigned apk = apk_cur;
        apk_cur = avgpk[(t + 2 <= 120) ? (t + 2) : 120];

        // ---- B fragment: 2 direct ds_read_b128, NO perms ----
        const bf16x8 Bhi = *(const bf16x8*)(bh + s * 40 + 8 * quad);
        const bf16x8 Blo = *(const bf16x8*)(bl + s * 40 + 8 * quad);

        // ---- 12 MFMAs: D = Ahi*Bhi + Ahi*Blo + Alo*Bhi + projb ----
        f32x4 D[4];
#pragma unroll
        for (int T = 0; T < 4; T++)
            D[T] = __builtin_amdgcn_mfma_f32_16x16x32_bf16(Alo[T], Bhi, projb[T], 0, 0, 0);
#pragma unroll
        for (int T = 0; T < 4; T++)
            D[T] = __builtin_amdgcn_mfma_f32_16x16x32_bf16(Ahi[T], Blo, D[T], 0, 0, 0);
#pragma unroll
        for (int T = 0; T < 4; T++)
            D[T] = __builtin_amdgcn_mfma_f32_16x16x32_bf16(Ahi[T], Bhi, D[T], 0, 0, 0);

        // ---- LSTM2 cell for step t-1 (wave1 local tile3 = rows 120..123) ----
        if (wv == 1 && t >= 1 && quad == 2) {
            const float g0 = fmaf(h2, whs0, D[3][0]);
            const float g1 = fmaf(h2, whs1, D[3][1]);
            const float g2 = fmaf(h2, whs2, D[3][2]);
            const float g3 = fmaf(h2, whs3, D[3][3]);
            c2 = sig2(g1) * c2 + sig2(g0) * tanh2(g2);
            h2 = sig2(g3) * tanh2(c2 * (-2.0f * LOG2E));
            out_s[s * 124 + (t - 1)] = h2;
        }

        // ---- LSTM1 activations (u=16wv+4T+quad), UNGUARDED; paired h-rcp ----
        if (t < 120) {
            float s2a[4], Ba[4], hka[4];
#pragma unroll
            for (int T = 0; T < 4; T++) {
                const float ei = __builtin_amdgcn_exp2f(D[T][0]);
                const float ef = __builtin_amdgcn_exp2f(D[T][1]);
                const float eg = __builtin_amdgcn_exp2f(D[T][2]);
                const float eo = __builtin_amdgcn_exp2f(D[T][3]);
                const float pi_ = 1.0f + ei, pf = 1.0f + ef;
                const float pg  = 1.0f + eg, po = 1.0f + eo;
                const float pig = pi_ * pg;
                const float num = fmaf(c1[T], pig, (1.0f - eg) * pf);
                const float ck  = num * __builtin_amdgcn_rcpf(pf * pig);
                c1[T] = ck;
                float carg = -2.0f * LOG2E * ck;
                carg = fminf(fmaxf(carg, -20.0f), 20.0f);
                const float ec = __builtin_amdgcn_exp2f(carg);
                s2a[T] = 1.0f - ec;
                Ba[T]  = po * (1.0f + ec);
            }
            // paired reciprocals: (0,1) both always live; (2,3) T=3 may be dead
            {
                const float P01 = __builtin_amdgcn_rcpf(Ba[0] * Ba[1]);
                hka[0] = s2a[0] * (Ba[1] * P01);
                hka[1] = s2a[1] * (Ba[0] * P01);
                const int u3 = 16 * wv + 12 + quad;
                const float B3e = (u3 < 30) ? Ba[3] : 1.0f;
                const float P23 = __builtin_amdgcn_rcpf(Ba[2] * B3e);
                hka[2] = s2a[2] * (B3e * P23);
                hka[3] = s2a[3] * (Ba[2] * P23);
            }
#pragma unroll
            for (int T = 0; T < 4; T++) {
                const int u = 16 * wv + 4 * T + quad;
                const unsigned hbits = __float_as_uint(hka[T]);
                const float rem = hka[T] - __uint_as_float(hbits & 0xffff0000u);
                unsigned hi16 = hbits >> 16;
                unsigned lo16 = __float_as_uint(rem) >> 16;
                if (T == 3) {                       // only T=3 can hit u>=30
                    if (u == 30) { hi16 = apk & 0xffffu; lo16 = apk >> 16; }
                    else if (u == 31) { hi16 = 0u; lo16 = 0u; }
                }
                nh[s * 40 + u] = (unsigned short)hi16;
                nl[s * 40 + u] = (unsigned short)lo16;
            }
            __syncthreads();                        // h_t halves visible to both waves
        }
    }

    __syncthreads();
    // ---- coalesced flush: 16 seq x 120 t = 480 float4 by 128 threads ----
    float* outb = out + (size_t)blockIdx.x * 16 * 120;
#pragma unroll
    for (int it = 0; it < 4; it++) {
        const int fi = it * 128 + tid;
        if (fi < 480) {
            const int sq = fi / 30, j = fi % 30;
            const float4 v = *reinterpret_cast<const float4*>(&out_s[sq * 124 + j * 4]);
            *reinterpret_cast<float4*>(&outb[sq * 120 + j * 4]) = v;
        }
    }
}

extern "C" void kernel_launch(void* const* d_in, const int* in_sizes, int n_in,
                              void* d_out, int out_size, void* d_ws, size_t ws_size,
                              hipStream_t stream) {
    (void)in_sizes; (void)n_in; (void)out_size; (void)ws_size;
    const float* feat  = (const float*)d_in[0];
    const float* w_ih1 = (const float*)d_in[1];
    const float* w_hh1 = (const float*)d_in[2];
    const float* b1    = (const float*)d_in[3];
    const float* w_ih2 = (const float*)d_in[4];
    const float* w_hh2 = (const float*)d_in[5];
    const float* b2    = (const float*)d_in[6];
    float* ws  = (float*)d_ws;
    float* out = (float*)d_out;

    hipLaunchKernelGGL(pack_weights, dim3(1), dim3(256), 0, stream,
                       w_ih1, w_hh1, b1, w_ih2, b2, ws);
    hipLaunchKernelGGL(lstm_mfma_kernel, dim3(2048), dim3(128), 0, stream,
                       feat, w_hh2, ws, out);
}